// Round 11
// baseline (402.229 us; speedup 1.0000x reference)
//
#include <hip/hip_runtime.h>
#include <math.h>

#define Bn 512
#define Tn 1024
#define Nn 64
#define LOG2E_F 1.44269504088896340736f
#define LN2_F   0.69314718055994530942f

__device__ __forceinline__ float wave_max(float v) {
    #pragma unroll
    for (int o = 32; o > 0; o >>= 1) v = fmaxf(v, __shfl_xor(v, o));
    return v;
}
__device__ __forceinline__ float wave_sum(float v) {
    #pragma unroll
    for (int o = 32; o > 0; o >>= 1) v += __shfl_xor(v, o);
    return v;
}

// ---------------------------------------------------------------------------
// R11 structure: ONE wave runs BOTH chains (fwd+bwd of the same sequence),
// interleaved step-by-step. Rationale (R10 counters): chain is latency-bound
// (pk_fma halved issue, VALUBusy 21->15%, time flat) -- each chain uses only
// ~20% of its SIMD's issue slots, so two chains share one SIMD for free.
// This frees 512 SIMDs: grid = 512 recursion + 512 score blocks = 1024 waves
// = 1/SIMD, ZERO sharing (R7's score waves cost +22us in contention).
// f,g land in the same wave -> logZ computed in-wave; combine shrinks to
// out[b] = ssc[b] - zres[b] (both staged in ws; avoids same-dispatch race).
//
// Step cadence budget (R4: 687 cyc/step, latency-bound):
//   ds_write->ds_read ~140 | 8x ds_read_b128 ~96 | FMA 128 | shfl ~110 |
//   misc/waits ~200. Issue demand of 2 chains = ~330 < 687 -> cadence holds.
// ---------------------------------------------------------------------------

// one recursion step; exact fp32. Single wave: LDS queue is in-order per
// wave, so write -> reads needs no barrier. (R4/R7 measured-best form.)
#define STEPD(QV, SH, EF, BWDV, EXV) do {                          \
    SH[j] = (BWDV) ? ((EXV) * QV) : QV;                            \
    float _aP0 = 0.f, _aP1 = 0.f, _aQ0 = 0.f, _aQ1 = 0.f;         \
    _Pragma("unroll")                                              \
    for (int _cb = 0; _cb < 8; _cb += 2) {                         \
        const float4 _u0 = *(const float4*)&SH[(g << 5) + (_cb << 2)];      \
        const float4 _u1 = *(const float4*)&SH[(g << 5) + ((_cb + 1) << 2)];\
        _aP0 = fmaf(_u0.x, EF[4*_cb + 0], _aP0);                   \
        _aQ0 = fmaf(_u0.x, EF[32 + 4*_cb + 0], _aQ0);              \
        _aP0 = fmaf(_u0.y, EF[4*_cb + 1], _aP0);                   \
        _aQ0 = fmaf(_u0.y, EF[32 + 4*_cb + 1], _aQ0);              \
        _aP0 = fmaf(_u0.z, EF[4*_cb + 2], _aP0);                   \
        _aQ0 = fmaf(_u0.z, EF[32 + 4*_cb + 2], _aQ0);              \
        _aP0 = fmaf(_u0.w, EF[4*_cb + 3], _aP0);                   \
        _aQ0 = fmaf(_u0.w, EF[32 + 4*_cb + 3], _aQ0);              \
        _aP1 = fmaf(_u1.x, EF[4*_cb + 4], _aP1);                   \
        _aQ1 = fmaf(_u1.x, EF[32 + 4*_cb + 4], _aQ1);              \
        _aP1 = fmaf(_u1.y, EF[4*_cb + 5], _aP1);                   \
        _aQ1 = fmaf(_u1.y, EF[32 + 4*_cb + 5], _aQ1);              \
        _aP1 = fmaf(_u1.z, EF[4*_cb + 6], _aP1);                   \
        _aQ1 = fmaf(_u1.z, EF[32 + 4*_cb + 6], _aQ1);              \
        _aP1 = fmaf(_u1.w, EF[4*_cb + 7], _aP1);                   \
        _aQ1 = fmaf(_u1.w, EF[32 + 4*_cb + 7], _aQ1);              \
    }                                                              \
    float _aP = _aP0 + _aP1, _aQ = _aQ0 + _aQ1;                    \
    float _u = lo32 ? _aP : _aQ;                                   \
    float _w = lo32 ? _aQ : _aP;                                   \
    float _s = _u + __shfl_xor(_w, 32);                            \
    QV = (BWDV) ? _s : ((EXV) * _s);                               \
} while (0)

// clamped row index: keeps every prefetch load unconditional + in-bounds
__device__ __forceinline__ int clamp_row(int tt, int Lm1) {
    return tt < 0 ? 0 : (tt > Lm1 ? Lm1 : tt);
}

template <bool FULL>
__global__ __launch_bounds__(64, 1) void crf_main(
    const float* __restrict__ inputs, const float* __restrict__ trans,
    const int* __restrict__ tags, const int* __restrict__ lens,
    float* __restrict__ ws, float* __restrict__ out)
{
    const int j = threadIdx.x;

    // ---- score role: blocks [Bn, 2Bn) -- own SIMDs, fully parallel
    if (!FULL && blockIdx.x >= Bn) {
        const int b = blockIdx.x - Bn;
        const int L = lens[b];
        const int* tagb = tags + b * Tn;
        const float* inb = inputs + (size_t)b * Tn * Nn;
        float sacc = 0.f;
        #pragma unroll
        for (int i = 0; i < Tn / 64; ++i) {
            int t  = j + 64 * i;
            int tm = t > 0 ? t - 1 : 0;
            int tg = tagb[t];
            int tp = tagb[tm];
            float un = inb[t * Nn + tg];
            float bi = trans[tp * Nn + tg];
            float c  = un + ((t >= 1) ? bi : 0.f);
            sacc += (t < L) ? c : 0.f;
        }
        float sc = wave_sum(sacc);
        if (j == 0) ws[Bn + b] = sc;          // ssc
        return;
    }

    const int g = j >> 5;            // input K-half this lane reads
    const int p = j & 31;
    const bool lo32 = (j < 32);
    const int b = blockIdx.x;
    const int L = lens[b];
    const int Lm1 = L - 1;
    const float* inb = inputs + (size_t)b * Tn * Nn;

    __shared__ float trsh[64 * 65];
    __shared__ __align__(16) float shqF[64];
    __shared__ __align__(16) float shqB[64];

    // EfF[c]: input (g*32+c) -> out p (fwd, E[i][o]); EfF[32+c]: -> out p+32
    float EfF[64];
    #pragma unroll
    for (int c = 0; c < 32; ++c) {
        EfF[c]      = exp2f(trans[(g * 32 + c) * 64 + p     ] * LOG2E_F);
        EfF[32 + c] = exp2f(trans[(g * 32 + c) * 64 + p + 32] * LOG2E_F);
    }
    // bwd: E[o][i] via LDS transpose (setup only)
    float EfB[64];
    if (!FULL) {
        #pragma unroll
        for (int i = 0; i < 64; ++i) trsh[i * 65 + j] = trans[i * 64 + j];
        __syncthreads();
        #pragma unroll
        for (int c = 0; c < 32; ++c) {
            EfB[c]      = exp2f(trsh[p        * 65 + g * 32 + c] * LOG2E_F);
            EfB[32 + c] = exp2f(trsh[(p + 32) * 65 + g * 32 + c] * LOG2E_F);
        }
    }

    // ---- chain A (fwd) init
    float qf, basef;
    {
        float x0 = inb[j];
        float m = wave_max(x0);
        qf = exp2f((x0 - m) * LOG2E_F);
        basef = m;
    }
    const int tf = L >> 1;
    const int nf = FULL ? Lm1 : tf;             // fwd steps
    const int nb = FULL ? 0 : (Lm1 - tf);       // bwd steps (nf-nb in {0,1})

    // ---- chain B (bwd) init
    float qb = 1.f, baseb = 0.f;

    // prefetch pipelines (unconditional clamped loads, R3 lesson)
    float xcf[8], xcb[8];
    #pragma unroll
    for (int d = 0; d < 8; ++d) {
        xcf[d] = inb[clamp_row(1 + d, Lm1) * Nn + j];
        xcb[d] = inb[clamp_row(Lm1 - d, Lm1) * Nn + j];
    }

    int k = 0, tA = 1, tB = Lm1;
    float pendf = 1.0f, pendb = 1.0f;

    if (FULL) {
        // single-chain full-length path (fallback)
        while (k + 8 <= nf) {
            float xn[8];
            #pragma unroll
            for (int d = 0; d < 8; ++d)
                xn[d] = inb[clamp_row(tA + 8 + d, Lm1) * Nn + j];
            float exc[8];
            #pragma unroll
            for (int u = 0; u < 8; ++u)
                exc[u] = exp2f(fmaf(xcf[u], LOG2E_F, -6.0f));
            exc[2] *= pendf;
            #pragma unroll
            for (int u = 0; u < 8; ++u) STEPD(qf, shqF, EfF, false, exc[u]);
            float m = wave_max(qf);
            basef += __logf(m);
            pendf = 1.0f / m;
            #pragma unroll
            for (int d = 0; d < 8; ++d) xcf[d] = xn[d];
            k += 8; tA += 8;
        }
        qf *= pendf;
        #pragma unroll
        for (int u = 0; u < 8; ++u) {
            if (k + u < nf) {
                float exu = exp2f(fmaf(xcf[u], LOG2E_F, -6.0f));
                STEPD(qf, shqF, EfF, false, exu);
            }
        }
        float m = wave_max(qf);
        qf *= (1.0f / m);
        basef += __logf(m) + LN2_F * 6.0f * (float)nf;
        float ssum = wave_sum(qf);
        if (j == 0) out[b] -= (basef + __logf(ssum));
        return;
    }

    // ---- joint interleaved loop: both chains, 8 steps per superstep
    while (k + 8 <= nb) {
        float xnf[8], xnb[8];
        #pragma unroll
        for (int d = 0; d < 8; ++d) {
            xnf[d] = inb[clamp_row(tA + 8 + d, Lm1) * Nn + j];
            xnb[d] = inb[clamp_row(tB - (8 + d), Lm1) * Nn + j];
        }
        float excf[8], excb[8];
        #pragma unroll
        for (int u = 0; u < 8; ++u) {
            excf[u] = exp2f(fmaf(xcf[u], LOG2E_F, -6.0f));
            excb[u] = exp2f(fmaf(xcb[u], LOG2E_F, -6.0f));
        }
        excf[2] *= pendf;
        excb[2] *= pendb;
        #pragma unroll
        for (int u = 0; u < 8; ++u) {
            STEPD(qf, shqF, EfF, false, excf[u]);
            STEPD(qb, shqB, EfB, true,  excb[u]);
        }
        float mf = wave_max(qf);
        basef += __logf(mf); pendf = 1.0f / mf;
        float mb = wave_max(qb);
        baseb += __logf(mb); pendb = 1.0f / mb;
        #pragma unroll
        for (int d = 0; d < 8; ++d) { xcf[d] = xnf[d]; xcb[d] = xnb[d]; }
        k += 8; tA += 8; tB -= 8;
    }
    qf *= pendf; qb *= pendb;
    // tails (<=8 steps each; nf-k <= 8 since nf-nb <= 1)
    #pragma unroll
    for (int u = 0; u < 8; ++u) {
        if (k + u < nf) {
            float exu = exp2f(fmaf(xcf[u], LOG2E_F, -6.0f));
            STEPD(qf, shqF, EfF, false, exu);
        }
    }
    #pragma unroll
    for (int u = 0; u < 8; ++u) {
        if (k + u < nb) {
            float exu = exp2f(fmaf(xcb[u], LOG2E_F, -6.0f));
            STEPD(qb, shqB, EfB, true, exu);
        }
    }

    // final renorms + 1/64-per-step corrections, then in-wave combine
    {
        float mf = wave_max(qf);
        qf *= (1.0f / mf);
        basef += __logf(mf) + LN2_F * 6.0f * (float)nf;
        float mb = wave_max(qb);
        qb *= (1.0f / mb);
        baseb += __logf(mb) + LN2_F * 6.0f * (float)nb;
        float dot = wave_sum(qf * qb);
        if (j == 0) ws[b] = basef + baseb + __logf(dot);   // zres
    }
}

// ---------------------------------------------------------------------------
// final: out[b] = score - logZ (both staged in ws by the main dispatch)
// ---------------------------------------------------------------------------
__global__ __launch_bounds__(64) void crf_comb2(
    const float* __restrict__ ws, float* __restrict__ out)
{
    const int idx = blockIdx.x * 64 + threadIdx.x;
    if (idx < Bn) out[idx] = ws[Bn + idx] - ws[idx];
}

// ---------------------------------------------------------------------------
// scores standalone (fallback path only)
// ---------------------------------------------------------------------------
__global__ __launch_bounds__(256) void crf_scores(
    const float* __restrict__ inputs, const float* __restrict__ trans,
    const int* __restrict__ tags, const int* __restrict__ lens,
    float* __restrict__ out)
{
    const int b = blockIdx.x;
    const int L = lens[b];
    const int* tagb = tags + b * Tn;
    const float* inb = inputs + (size_t)b * Tn * Nn;

    float acc = 0.f;
    for (int t = threadIdx.x; t < L; t += 256) {
        int tg = tagb[t];
        acc += inb[t * Nn + tg];
        if (t >= 1) acc += trans[tagb[t - 1] * Nn + tg];
    }
    acc = wave_sum(acc);
    __shared__ float red[4];
    if ((threadIdx.x & 63) == 0) red[threadIdx.x >> 6] = acc;
    __syncthreads();
    if (threadIdx.x == 0) out[b] = (red[0] + red[1]) + (red[2] + red[3]);
}

extern "C" void kernel_launch(void* const* d_in, const int* in_sizes, int n_in,
                              void* d_out, int out_size, void* d_ws, size_t ws_size,
                              hipStream_t stream) {
    const float* inputs = (const float*)d_in[0];
    const float* trans  = (const float*)d_in[1];
    const int*   tags   = (const int*)d_in[2];
    const int*   lens   = (const int*)d_in[3];
    float* out = (float*)d_out;
    float* ws  = (float*)d_ws;

    const size_t need = (size_t)(2 * Bn) * sizeof(float);
    if (ws_size >= need) {
        // 512 dual-chain recursion blocks + 512 score blocks = 1024 waves
        crf_main<false><<<2 * Bn, 64, 0, stream>>>(inputs, trans, tags, lens, ws, out);
        crf_comb2<<<(Bn + 63) / 64, 64, 0, stream>>>(ws, out);
    } else {
        // workspace too small: score kernel + full-length fwd recursion
        crf_scores<<<Bn, 256, 0, stream>>>(inputs, trans, tags, lens, out);
        crf_main<true><<<Bn, 64, 0, stream>>>(inputs, trans, tags, lens, ws, out);
    }
}